// Round 2
// baseline (1018.042 us; speedup 1.0000x reference)
//
#include <hip/hip_runtime.h>
#include <math.h>

#define NA 500000
#define NE 1000000
#define NB 100000
#define HID 128
#define TILE 64
#define SHS 68          // padded LDS stride for [k][atom] tile (breaks bank conflicts, keeps 16B align)
#define NCHUNK 489      // ceil(NA / 1024)

static __device__ __forceinline__ float relu_add(float a, float b) {
    float s = a + b;
    return s > 0.f ? s : 0.f;
}

// ---- K0: per-atom context flag + per-block atom count ----
__global__ __launch_bounds__(256) void k_ctx(const int* __restrict__ block_ids,
                                             const int* __restrict__ gmask,
                                             int* __restrict__ ctx,
                                             int* __restrict__ cnt) {
    int i = blockIdx.x * 256 + threadIdx.x;
    if (i < NA) {
        int b = block_ids[i];
        ctx[i] = (gmask[b] == 0) ? 1 : 0;
        atomicAdd(&cnt[b], 1);
    }
}

// ---- K1: histogram of kept edges by dst ----
__global__ __launch_bounds__(256) void k_hist(const int* __restrict__ bonds,
                                              const int* __restrict__ ctx,
                                              int* __restrict__ deg) {
    int e = blockIdx.x * 256 + threadIdx.x;
    if (e < NE) {
        int s = bonds[3 * e + 0];
        int d = bonds[3 * e + 1];
        if (ctx[s] && ctx[d]) atomicAdd(&deg[d], 1);
    }
}

// ---- K2a: per-chunk (1024 elems) exclusive scan ----
__global__ __launch_bounds__(256) void k_scan_chunks(const int* __restrict__ deg,
                                                     int* __restrict__ off,
                                                     int* __restrict__ tot) {
    __shared__ int sd[256];
    int t = threadIdx.x;
    int base = blockIdx.x * 1024 + t * 4;
    int v0 = 0, v1 = 0, v2 = 0, v3 = 0;
    if (base + 0 < NA) v0 = deg[base + 0];
    if (base + 1 < NA) v1 = deg[base + 1];
    if (base + 2 < NA) v2 = deg[base + 2];
    if (base + 3 < NA) v3 = deg[base + 3];
    int s = v0 + v1 + v2 + v3;
    sd[t] = s;
    __syncthreads();
    for (int o = 1; o < 256; o <<= 1) {
        int x = (t >= o) ? sd[t - o] : 0;
        __syncthreads();
        sd[t] += x;
        __syncthreads();
    }
    int run = sd[t] - s;                 // exclusive prefix for this thread
    if (t == 255) tot[blockIdx.x] = sd[255];
    if (base + 0 < NA) { off[base + 0] = run; run += v0; }
    if (base + 1 < NA) { off[base + 1] = run; run += v1; }
    if (base + 2 < NA) { off[base + 2] = run; run += v2; }
    if (base + 3 < NA) { off[base + 3] = run; }
}

// ---- K2b: scan the chunk totals (single block) ----
__global__ __launch_bounds__(512) void k_scan_tot(int* __restrict__ tot,
                                                  int* __restrict__ off) {
    __shared__ int sd[512];
    int t = threadIdx.x;
    int v = (t < NCHUNK) ? tot[t] : 0;
    sd[t] = v;
    __syncthreads();
    for (int o = 1; o < 512; o <<= 1) {
        int x = (t >= o) ? sd[t - o] : 0;
        __syncthreads();
        sd[t] += x;
        __syncthreads();
    }
    if (t < NCHUNK) tot[t] = sd[t] - v;  // exclusive chunk offsets
    if (t == 511) off[NA] = sd[511];     // grand total of kept edges
}

// ---- K2c: finalize offsets + init scatter cursors ----
__global__ __launch_bounds__(256) void k_finish(int* __restrict__ off,
                                                const int* __restrict__ tot,
                                                int* __restrict__ cur) {
    int i = blockIdx.x * 256 + threadIdx.x;
    if (i < NA) {
        int f = off[i] + tot[i >> 10];
        off[i] = f;
        cur[i] = f;
    }
}

// ---- K3: scatter kept edges (combo id) into dst-sorted list ----
__global__ __launch_bounds__(256) void k_scatter(const int* __restrict__ bonds,
                                                 const int* __restrict__ ctx,
                                                 const int* __restrict__ A,
                                                 int* __restrict__ cur,
                                                 int* __restrict__ srt) {
    int e = blockIdx.x * 256 + threadIdx.x;
    if (e < NE) {
        int s = bonds[3 * e + 0];
        int d = bonds[3 * e + 1];
        int bt = bonds[3 * e + 2];
        if (ctx[s] && ctx[d]) {
            int p = atomicAdd(&cur[d], 1);
            srt[p] = (A[s] << 3) | bt;   // A < 128, bt < 5
        }
    }
}

// ---- K4: fused h-build + 2-layer MLP + atomic block-sum ----
__global__ __launch_bounds__(256) void k_atom_mlp(
    const int* __restrict__ A, const int* __restrict__ block_ids,
    const int* __restrict__ off, const int* __restrict__ srt,
    const float* __restrict__ atom_table, const float* __restrict__ bond_table,
    const float* __restrict__ epsp,
    const float* __restrict__ W1, const float* __restrict__ b1,
    const float* __restrict__ W2, const float* __restrict__ b2,
    float* __restrict__ out)
{
    __shared__ float sH[HID * SHS];   // [k][atom] tile, 34 KB
    __shared__ float sW[32 * HID];    // quarter of a weight matrix, 16 KB
    const int tid = threadIdx.x;

    // ---- phase B: build h rows (transposed) into sH ----
    {
        const int al = tid >> 2;            // atom-local 0..63
        const int ks = (tid & 3) * 32;      // this thread's k-segment
        const int g = blockIdx.x * TILE + al;
        float hacc[32];
#pragma unroll
        for (int j = 0; j < 32; ++j) hacc[j] = 0.f;
        if (g < NA) {
            const float ope = 1.0f + epsp[0];
            const float4* at4 = (const float4*)(atom_table + A[g] * HID + ks);
#pragma unroll
            for (int j = 0; j < 8; ++j) {
                float4 v = at4[j];
                hacc[4 * j + 0] = ope * v.x;
                hacc[4 * j + 1] = ope * v.y;
                hacc[4 * j + 2] = ope * v.z;
                hacc[4 * j + 3] = ope * v.w;
            }
            const int e0 = off[g], e1 = off[g + 1];
            for (int e = e0; e < e1; ++e) {
                const int cb = srt[e];
                const float4* a24 = (const float4*)(atom_table + (cb >> 3) * HID + ks);
                const float4* bt4 = (const float4*)(bond_table + (cb & 7) * HID + ks);
#pragma unroll
                for (int j = 0; j < 8; ++j) {
                    float4 x = a24[j];
                    float4 y = bt4[j];
                    hacc[4 * j + 0] += relu_add(x.x, y.x);
                    hacc[4 * j + 1] += relu_add(x.y, y.y);
                    hacc[4 * j + 2] += relu_add(x.z, y.z);
                    hacc[4 * j + 3] += relu_add(x.w, y.w);
                }
            }
        }
#pragma unroll
        for (int j = 0; j < 32; ++j) sH[(ks + j) * SHS + al] = hacc[j];
    }
    __syncthreads();

    const int c0 = (tid & 31) * 4;      // 4 output columns
    const int a0 = (tid >> 5) * 8;      // 8 atoms
    float acc[8][4];

    // ---- matmul1: out1 = relu(h @ W1 + b1) ----
#pragma unroll
    for (int j = 0; j < 8; ++j)
#pragma unroll
        for (int c = 0; c < 4; ++c) acc[j][c] = 0.f;

    for (int q = 0; q < 4; ++q) {
        for (int i = tid * 4; i < 32 * HID; i += 1024)
            *(float4*)&sW[i] = *(const float4*)&W1[q * 32 * HID + i];
        __syncthreads();
#pragma unroll 8
        for (int kk = 0; kk < 32; ++kk) {
            const float4 w = *(const float4*)&sW[kk * HID + c0];
            const float* hr = &sH[(q * 32 + kk) * SHS + a0];
            const float4 h0 = *(const float4*)hr;
            const float4 h1 = *(const float4*)(hr + 4);
            const float hv[8] = {h0.x, h0.y, h0.z, h0.w, h1.x, h1.y, h1.z, h1.w};
#pragma unroll
            for (int j = 0; j < 8; ++j) {
                acc[j][0] = fmaf(hv[j], w.x, acc[j][0]);
                acc[j][1] = fmaf(hv[j], w.y, acc[j][1]);
                acc[j][2] = fmaf(hv[j], w.z, acc[j][2]);
                acc[j][3] = fmaf(hv[j], w.w, acc[j][3]);
            }
        }
        __syncthreads();
    }

    // bias + relu, write transposed back into sH
    {
        const float4 bv = *(const float4*)&b1[c0];
        float r[8][4];
#pragma unroll
        for (int j = 0; j < 8; ++j) {
            r[j][0] = fmaxf(acc[j][0] + bv.x, 0.f);
            r[j][1] = fmaxf(acc[j][1] + bv.y, 0.f);
            r[j][2] = fmaxf(acc[j][2] + bv.z, 0.f);
            r[j][3] = fmaxf(acc[j][3] + bv.w, 0.f);
        }
#pragma unroll
        for (int ci = 0; ci < 4; ++ci) {
            float4 lo = make_float4(r[0][ci], r[1][ci], r[2][ci], r[3][ci]);
            float4 hi = make_float4(r[4][ci], r[5][ci], r[6][ci], r[7][ci]);
            *(float4*)&sH[(c0 + ci) * SHS + a0]     = lo;
            *(float4*)&sH[(c0 + ci) * SHS + a0 + 4] = hi;
        }
    }
    __syncthreads();

    // ---- matmul2: h2 = t @ W2 + b2 ----
#pragma unroll
    for (int j = 0; j < 8; ++j)
#pragma unroll
        for (int c = 0; c < 4; ++c) acc[j][c] = 0.f;

    for (int q = 0; q < 4; ++q) {
        for (int i = tid * 4; i < 32 * HID; i += 1024)
            *(float4*)&sW[i] = *(const float4*)&W2[q * 32 * HID + i];
        __syncthreads();
#pragma unroll 8
        for (int kk = 0; kk < 32; ++kk) {
            const float4 w = *(const float4*)&sW[kk * HID + c0];
            const float* hr = &sH[(q * 32 + kk) * SHS + a0];
            const float4 h0 = *(const float4*)hr;
            const float4 h1 = *(const float4*)(hr + 4);
            const float hv[8] = {h0.x, h0.y, h0.z, h0.w, h1.x, h1.y, h1.z, h1.w};
#pragma unroll
            for (int j = 0; j < 8; ++j) {
                acc[j][0] = fmaf(hv[j], w.x, acc[j][0]);
                acc[j][1] = fmaf(hv[j], w.y, acc[j][1]);
                acc[j][2] = fmaf(hv[j], w.z, acc[j][2]);
                acc[j][3] = fmaf(hv[j], w.w, acc[j][3]);
            }
        }
        __syncthreads();
    }

    // ---- accumulate into per-block sums ----
    {
        const float4 b2v = *(const float4*)&b2[c0];
        const int gbase = blockIdx.x * TILE + a0;
#pragma unroll
        for (int j = 0; j < 8; ++j) {
            const int g = gbase + j;
            if (g < NA) {
                float* o = out + (size_t)block_ids[g] * HID + c0;
                atomicAdd(o + 0, acc[j][0] + b2v.x);
                atomicAdd(o + 1, acc[j][1] + b2v.y);
                atomicAdd(o + 2, acc[j][2] + b2v.z);
                atomicAdd(o + 3, acc[j][3] + b2v.w);
            }
        }
    }
}

// ---- K5: normalize by sqrt(count), apply mask ----
__global__ __launch_bounds__(256) void k_norm(float* __restrict__ out,
                                              const int* __restrict__ cnt,
                                              const int* __restrict__ gmask) {
    int i = blockIdx.x * 256 + threadIdx.x;
    if (i < NB * HID) {
        int b = i >> 7;
        float v = 0.f;
        if (gmask[b] == 0) {
            int c = cnt[b];
            if (c < 1) c = 1;
            v = out[i] / sqrtf((float)c);
        }
        out[i] = v;
    }
}

extern "C" void kernel_launch(void* const* d_in, const int* in_sizes, int n_in,
                              void* d_out, int out_size, void* d_ws, size_t ws_size,
                              hipStream_t stream) {
    const int* A          = (const int*)d_in[0];
    const int* bonds      = (const int*)d_in[1];
    const int* block_ids  = (const int*)d_in[2];
    const int* gmask      = (const int*)d_in[3];
    const float* atom_table = (const float*)d_in[4];
    const float* bond_table = (const float*)d_in[5];
    const float* eps      = (const float*)d_in[6];
    const float* W1       = (const float*)d_in[7];
    const float* b1       = (const float*)d_in[8];
    const float* W2       = (const float*)d_in[9];
    const float* b2       = (const float*)d_in[10];
    float* out = (float*)d_out;
    char* ws = (char*)d_ws;

    // ws layout (bytes); total ~12.4 MB
    int* deg = (int*)(ws + 0);          // [NA]
    int* off = (int*)(ws + 2000000);    // [NA+1]
    int* cur = (int*)(ws + 4000064);    // [NA]
    int* tot = (int*)(ws + 6000128);    // [NCHUNK]
    int* ctx = (int*)(ws + 6004224);    // [NA]
    int* srt = (int*)(ws + 8004224);    // [NE]
    int* cnt = (int*)(ws + 12004224);   // [NB]

    hipMemsetAsync(deg, 0, NA * 4, stream);
    hipMemsetAsync(cnt, 0, NB * 4, stream);
    hipMemsetAsync(out, 0, (size_t)NB * HID * 4, stream);

    k_ctx<<<(NA + 255) / 256, 256, 0, stream>>>(block_ids, gmask, ctx, cnt);
    k_hist<<<(NE + 255) / 256, 256, 0, stream>>>(bonds, ctx, deg);
    k_scan_chunks<<<NCHUNK, 256, 0, stream>>>(deg, off, tot);
    k_scan_tot<<<1, 512, 0, stream>>>(tot, off);
    k_finish<<<(NA + 255) / 256, 256, 0, stream>>>(off, tot, cur);
    k_scatter<<<(NE + 255) / 256, 256, 0, stream>>>(bonds, ctx, A, cur, srt);
    k_atom_mlp<<<(NA + TILE - 1) / TILE, 256, 0, stream>>>(
        A, block_ids, off, srt, atom_table, bond_table, eps, W1, b1, W2, b2, out);
    k_norm<<<(NB * HID + 255) / 256, 256, 0, stream>>>(out, cnt, gmask);
}

// Round 3
// 306.237 us; speedup vs baseline: 3.3244x; 3.3244x over previous
//
#include <hip/hip_runtime.h>
#include <math.h>

#define NA 500000
#define NE 1000000
#define NB 100000
#define HID 128
#define NCHUNK 489      // ceil(NA / 1024)
#define NT 7813         // ceil(NA / 64) — static grid; blocks past nctx early-exit

typedef __attribute__((ext_vector_type(8))) short bf16x8;
typedef __attribute__((ext_vector_type(4))) float f32x4;

// fp32 -> bf16 round-to-nearest-even
static __device__ __forceinline__ unsigned short bf1(float a) {
    unsigned ua = __float_as_uint(a);
    ua += 0x7fffu + ((ua >> 16) & 1u);
    return (unsigned short)(ua >> 16);
}
static __device__ __forceinline__ unsigned bfpack(float a, float b) {
    unsigned ua = __float_as_uint(a); ua += 0x7fffu + ((ua >> 16) & 1u);
    unsigned ub = __float_as_uint(b); ub += 0x7fffu + ((ub >> 16) & 1u);
    return (ua >> 16) | (ub & 0xffff0000u);
}

// ---- K0: per-atom context flag + per-block atom count ----
__global__ __launch_bounds__(256) void k_ctx(const int* __restrict__ block_ids,
                                             const int* __restrict__ gmask,
                                             int* __restrict__ ctx,
                                             int* __restrict__ cnt) {
    int i = blockIdx.x * 256 + threadIdx.x;
    if (i < NA) {
        int b = block_ids[i];
        ctx[i] = (gmask[b] == 0) ? 1 : 0;
        atomicAdd(&cnt[b], 1);
    }
}

// ---- K1: histogram of kept edges by dst ----
__global__ __launch_bounds__(256) void k_hist(const int* __restrict__ bonds,
                                              const int* __restrict__ ctx,
                                              int* __restrict__ deg) {
    int e = blockIdx.x * 256 + threadIdx.x;
    if (e < NE) {
        int s = bonds[3 * e + 0];
        int d = bonds[3 * e + 1];
        if (ctx[s] && ctx[d]) atomicAdd(&deg[d], 1);
    }
}

// ---- K2a: per-chunk (1024 elems) exclusive scan (generic src->dst) ----
__global__ __launch_bounds__(256) void k_scan_chunks(const int* __restrict__ src,
                                                     int* __restrict__ dst,
                                                     int* __restrict__ tot) {
    __shared__ int sd[256];
    int t = threadIdx.x;
    int base = blockIdx.x * 1024 + t * 4;
    int v0 = 0, v1 = 0, v2 = 0, v3 = 0;
    if (base + 0 < NA) v0 = src[base + 0];
    if (base + 1 < NA) v1 = src[base + 1];
    if (base + 2 < NA) v2 = src[base + 2];
    if (base + 3 < NA) v3 = src[base + 3];
    int s = v0 + v1 + v2 + v3;
    sd[t] = s;
    __syncthreads();
    for (int o = 1; o < 256; o <<= 1) {
        int x = (t >= o) ? sd[t - o] : 0;
        __syncthreads();
        sd[t] += x;
        __syncthreads();
    }
    int run = sd[t] - s;
    if (t == 255) tot[blockIdx.x] = sd[255];
    if (base + 0 < NA) { dst[base + 0] = run; run += v0; }
    if (base + 1 < NA) { dst[base + 1] = run; run += v1; }
    if (base + 2 < NA) { dst[base + 2] = run; run += v2; }
    if (base + 3 < NA) { dst[base + 3] = run; }
}

// ---- K2b: scan the chunk totals (single block); total -> total_out[0] ----
__global__ __launch_bounds__(512) void k_scan_tot(int* __restrict__ tot,
                                                  int* __restrict__ total_out) {
    __shared__ int sd[512];
    int t = threadIdx.x;
    int v = (t < NCHUNK) ? tot[t] : 0;
    sd[t] = v;
    __syncthreads();
    for (int o = 1; o < 512; o <<= 1) {
        int x = (t >= o) ? sd[t - o] : 0;
        __syncthreads();
        sd[t] += x;
        __syncthreads();
    }
    if (t < NCHUNK) tot[t] = sd[t] - v;
    if (t == 511) total_out[0] = sd[511];
}

// ---- K2c: finalize edge offsets + init scatter cursors ----
__global__ __launch_bounds__(256) void k_finish(int* __restrict__ off,
                                                const int* __restrict__ tot,
                                                int* __restrict__ cur) {
    int i = blockIdx.x * 256 + threadIdx.x;
    if (i < NA) {
        int f = off[i] + tot[i >> 10];
        off[i] = f;
        cur[i] = f;
    }
}

// ---- K3: scatter kept edges (combo id) into dst-sorted list ----
__global__ __launch_bounds__(256) void k_scatter(const int* __restrict__ bonds,
                                                 const int* __restrict__ ctx,
                                                 const int* __restrict__ A,
                                                 int* __restrict__ cur,
                                                 int* __restrict__ srt) {
    int e = blockIdx.x * 256 + threadIdx.x;
    if (e < NE) {
        int s = bonds[3 * e + 0];
        int d = bonds[3 * e + 1];
        int bt = bonds[3 * e + 2];
        if (ctx[s] && ctx[d]) {
            int p = atomicAdd(&cur[d], 1);
            srt[p] = (A[s] << 3) | bt;
        }
    }
}

// ---- K2d: build compacted ctx-atom list ----
__global__ __launch_bounds__(256) void k_finish_c(const int* __restrict__ cpos,
                                                  const int* __restrict__ tot,
                                                  const int* __restrict__ ctx,
                                                  int* __restrict__ catom) {
    int i = blockIdx.x * 256 + threadIdx.x;
    if (i < NA && ctx[i]) catom[cpos[i] + tot[i >> 10]] = i;
}

// ---- Kw: W1,W2 (fp32 row-major [k][n]) -> bf16 col-major [n][k] ----
__global__ __launch_bounds__(256) void k_prepw(const float* __restrict__ W1,
                                               const float* __restrict__ W2,
                                               unsigned short* __restrict__ wt1,
                                               unsigned short* __restrict__ wt2) {
    int id = blockIdx.x * 256 + threadIdx.x;   // 0..16383
    int n = id >> 7, k = id & 127;
    wt1[id] = bf1(W1[k * HID + n]);
    wt2[id] = bf1(W2[k * HID + n]);
}

// ---- K4: fused h-build + MFMA 2-layer MLP + segmented block-sum ----
__global__ __launch_bounds__(256, 4) void k_mlp(
    const int* __restrict__ A, const int* __restrict__ block_ids,
    const int* __restrict__ off, const int* __restrict__ srt,
    const int* __restrict__ catom, const int* __restrict__ nctxp,
    const float* __restrict__ atom_table, const float* __restrict__ bond_table,
    const float* __restrict__ epsp,
    const unsigned short* __restrict__ wt1, const float* __restrict__ b1,
    const unsigned short* __restrict__ wt2, const float* __restrict__ b2,
    float* __restrict__ out)
{
    // [0,16K): h bf16 [64][128] swizzled; [16K,32K): h1 bf16 same layout;
    // reused as h2 f32 [64][128] (stride 512B) for the epilogue.
    __shared__ char lds[32768];
    __shared__ int sCat[64];
    __shared__ int sBid[64];

    const int nctx = nctxp[0];
    const int base = blockIdx.x * 64;
    if (base >= nctx) return;               // uniform exit
    const int tid = threadIdx.x;

    if (tid < 64) {
        int idx = base + tid;
        int g = (idx < nctx) ? catom[idx] : -1;
        sCat[tid] = g;
        sBid[tid] = (g >= 0) ? block_ids[g] : -1;
    }
    __syncthreads();

    // ---- phase B: build h rows (bf16, XOR-swizzled) ----
    {
        const int al = tid >> 2;            // atom-local 0..63
        const int ks4 = tid & 3;            // k-segment 0..3 (32 k each)
        const int g = sCat[al];
        float hacc[32];
#pragma unroll
        for (int j = 0; j < 32; ++j) hacc[j] = 0.f;
        if (g >= 0) {
            const float ope = 1.0f + epsp[0];
            const int ks = ks4 * 32;
            const float4* at4 = (const float4*)(atom_table + A[g] * HID + ks);
#pragma unroll
            for (int j = 0; j < 8; ++j) {
                float4 v = at4[j];
                hacc[4 * j + 0] = ope * v.x; hacc[4 * j + 1] = ope * v.y;
                hacc[4 * j + 2] = ope * v.z; hacc[4 * j + 3] = ope * v.w;
            }
            const int e0 = off[g], e1 = off[g + 1];
            for (int e = e0; e < e1; ++e) {
                const int cb = srt[e];
                const float4* a24 = (const float4*)(atom_table + (cb >> 3) * HID + ks);
                const float4* bt4 = (const float4*)(bond_table + (cb & 7) * HID + ks);
#pragma unroll
                for (int j = 0; j < 8; ++j) {
                    float4 x = a24[j], y = bt4[j];
                    hacc[4 * j + 0] += fmaxf(x.x + y.x, 0.f);
                    hacc[4 * j + 1] += fmaxf(x.y + y.y, 0.f);
                    hacc[4 * j + 2] += fmaxf(x.z + y.z, 0.f);
                    hacc[4 * j + 3] += fmaxf(x.w + y.w, 0.f);
                }
            }
        }
        char* rowp = lds + al * 256;
#pragma unroll
        for (int c = 0; c < 4; ++c) {
            uint4 u;
            u.x = bfpack(hacc[8 * c + 0], hacc[8 * c + 1]);
            u.y = bfpack(hacc[8 * c + 2], hacc[8 * c + 3]);
            u.z = bfpack(hacc[8 * c + 4], hacc[8 * c + 5]);
            u.w = bfpack(hacc[8 * c + 6], hacc[8 * c + 7]);
            int chunk = (ks4 * 4 + c) ^ (al & 7);
            *(uint4*)(rowp + chunk * 16) = u;
        }
    }
    __syncthreads();

    const int w = tid >> 6;                 // wave id: 16-atom row stripe
    const int lane = tid & 63;
    const int rA = w * 16 + (lane & 15);    // A-frag row (atom)
    const int g4 = lane >> 4;               // k-quarter within K=32
    const int colb = lane & 15;             // B-frag col within 16-tile

    // ---- GEMM1: h1 = relu(h @ W1 + b1) ----
    f32x4 acc1[8];
    {
        bf16x8 af[4];
#pragma unroll
        for (int k4 = 0; k4 < 4; ++k4) {
            int chunk = (k4 * 4 + g4) ^ (rA & 7);
            af[k4] = *(const bf16x8*)(lds + rA * 256 + chunk * 16);
        }
#pragma unroll
        for (int ct = 0; ct < 8; ++ct) {
            f32x4 a = {0.f, 0.f, 0.f, 0.f};
            const unsigned short* wp = wt1 + (ct * 16 + colb) * HID + g4 * 8;
#pragma unroll
            for (int k4 = 0; k4 < 4; ++k4) {
                bf16x8 bfr = *(const bf16x8*)(wp + k4 * 32);
                a = __builtin_amdgcn_mfma_f32_16x16x32_bf16(af[k4], bfr, a, 0, 0, 0);
            }
            acc1[ct] = a;
        }
    }
    // bias+relu -> h1 bf16 (each wave writes only its own 16-row stripe)
#pragma unroll
    for (int ct = 0; ct < 8; ++ct) {
        int col = ct * 16 + colb;
        float bv = b1[col];
        int cchunk = col >> 3;
        int within = (col & 7) * 2;
#pragma unroll
        for (int r = 0; r < 4; ++r) {
            int row = w * 16 + g4 * 4 + r;
            float v = fmaxf(acc1[ct][r] + bv, 0.f);
            int swz = cchunk ^ (row & 7);
            *(unsigned short*)(lds + 16384 + row * 256 + swz * 16 + within) = bf1(v);
        }
    }

    // ---- GEMM2: h2 = h1 @ W2 + b2 (reads only own stripe -> no barrier) ----
    f32x4 acc2[8];
    {
        bf16x8 af[4];
#pragma unroll
        for (int k4 = 0; k4 < 4; ++k4) {
            int chunk = (k4 * 4 + g4) ^ (rA & 7);
            af[k4] = *(const bf16x8*)(lds + 16384 + rA * 256 + chunk * 16);
        }
#pragma unroll
        for (int ct = 0; ct < 8; ++ct) {
            f32x4 a = {0.f, 0.f, 0.f, 0.f};
            const unsigned short* wp = wt2 + (ct * 16 + colb) * HID + g4 * 8;
#pragma unroll
            for (int k4 = 0; k4 < 4; ++k4) {
                bf16x8 bfr = *(const bf16x8*)(wp + k4 * 32);
                a = __builtin_amdgcn_mfma_f32_16x16x32_bf16(af[k4], bfr, a, 0, 0, 0);
            }
            acc2[ct] = a;
        }
    }
    __syncthreads();   // all waves done with h/h1 before overwriting with h2 f32

#pragma unroll
    for (int ct = 0; ct < 8; ++ct) {
        int col = ct * 16 + colb;
        float bv = b2[col];
#pragma unroll
        for (int r = 0; r < 4; ++r) {
            int row = w * 16 + g4 * 4 + r;
            *(float*)(lds + row * 512 + col * 4) = acc2[ct][r] + bv;
        }
    }
    __syncthreads();

    // ---- segmented block-sum over sorted sBid, then atomics per run ----
    {
        int c = tid & 127;
        int r0 = (tid >> 7) * 32;
        float run = 0.f;
        int curb = sBid[r0];
        for (int r = r0; r < r0 + 32; ++r) {
            int b = sBid[r];
            if (b != curb) {
                if (curb >= 0) atomicAdd(out + (size_t)curb * HID + c, run);
                run = 0.f;
                curb = b;
            }
            run += *(const float*)(lds + r * 512 + (c << 2));
        }
        if (curb >= 0) atomicAdd(out + (size_t)curb * HID + c, run);
    }
}

// ---- K5: normalize by sqrt(count), apply mask ----
__global__ __launch_bounds__(256) void k_norm(float* __restrict__ out,
                                              const int* __restrict__ cnt,
                                              const int* __restrict__ gmask) {
    int i = blockIdx.x * 256 + threadIdx.x;
    if (i < NB * HID) {
        int b = i >> 7;
        float v = 0.f;
        if (gmask[b] == 0) {
            int c = cnt[b];
            if (c < 1) c = 1;
            v = out[i] / sqrtf((float)c);
        }
        out[i] = v;
    }
}

extern "C" void kernel_launch(void* const* d_in, const int* in_sizes, int n_in,
                              void* d_out, int out_size, void* d_ws, size_t ws_size,
                              hipStream_t stream) {
    const int* A          = (const int*)d_in[0];
    const int* bonds      = (const int*)d_in[1];
    const int* block_ids  = (const int*)d_in[2];
    const int* gmask      = (const int*)d_in[3];
    const float* atom_table = (const float*)d_in[4];
    const float* bond_table = (const float*)d_in[5];
    const float* eps      = (const float*)d_in[6];
    const float* W1       = (const float*)d_in[7];
    const float* b1       = (const float*)d_in[8];
    const float* W2       = (const float*)d_in[9];
    const float* b2       = (const float*)d_in[10];
    float* out = (float*)d_out;
    char* ws = (char*)d_ws;

    // ws layout (bytes); total ~12.47 MB
    int* deg = (int*)(ws + 0);           // [NA]   (reused as cpos)
    int* off = (int*)(ws + 2000000);     // [NA+1]
    int* cur = (int*)(ws + 4000064);     // [NA]   (reused as catom)
    int* tot = (int*)(ws + 6000128);     // [NCHUNK] (reused for ctx scan)
    int* ctx = (int*)(ws + 6004224);     // [NA]
    int* srt = (int*)(ws + 8004224);     // [NE]
    int* cnt = (int*)(ws + 12004224);    // [NB]
    unsigned short* wt1 = (unsigned short*)(ws + 12404224);  // [128*128]
    unsigned short* wt2 = (unsigned short*)(ws + 12436992);  // [128*128]
    int* nctx = (int*)(ws + 12469760);   // [1]
    int* cpos  = deg;
    int* catom = cur;

    hipMemsetAsync(deg, 0, NA * 4, stream);
    hipMemsetAsync(cnt, 0, NB * 4, stream);
    hipMemsetAsync(out, 0, (size_t)NB * HID * 4, stream);

    k_ctx<<<(NA + 255) / 256, 256, 0, stream>>>(block_ids, gmask, ctx, cnt);
    k_hist<<<(NE + 255) / 256, 256, 0, stream>>>(bonds, ctx, deg);
    k_scan_chunks<<<NCHUNK, 256, 0, stream>>>(deg, off, tot);
    k_scan_tot<<<1, 512, 0, stream>>>(tot, off + NA);
    k_finish<<<(NA + 255) / 256, 256, 0, stream>>>(off, tot, cur);
    k_scatter<<<(NE + 255) / 256, 256, 0, stream>>>(bonds, ctx, A, cur, srt);
    // compaction (reuses deg->cpos, tot, cur->catom after they're dead)
    k_scan_chunks<<<NCHUNK, 256, 0, stream>>>(ctx, cpos, tot);
    k_scan_tot<<<1, 512, 0, stream>>>(tot, nctx);
    k_finish_c<<<(NA + 255) / 256, 256, 0, stream>>>(cpos, tot, ctx, catom);
    k_prepw<<<64, 256, 0, stream>>>(W1, W2, wt1, wt2);
    k_mlp<<<NT, 256, 0, stream>>>(A, block_ids, off, srt, catom, nctx,
                                  atom_table, bond_table, eps, wt1, b1, wt2, b2, out);
    k_norm<<<(NB * HID + 255) / 256, 256, 0, stream>>>(out, cnt, gmask);
}

// Round 4
// 200.786 us; speedup vs baseline: 5.0703x; 1.5252x over previous
//
#include <hip/hip_runtime.h>
#include <math.h>

#define NA 500000
#define NE 1000000
#define NB 100000
#define HID 128
#define NCHUNK 489      // ceil(NA / 1024)
#define NT 7813         // ceil(NA / 64) worst-case ctx tiles
#define NBT 1563        // ceil(NB / 64)
#define SST 132         // f32 LDS row stride (132 = 128 + 4 -> 2-way banks only)

typedef __attribute__((ext_vector_type(8))) short bf16x8;
typedef __attribute__((ext_vector_type(4))) float f32x4;

// fp32 -> bf16 round-to-nearest-even
static __device__ __forceinline__ unsigned short bf1(float a) {
    unsigned ua = __float_as_uint(a);
    ua += 0x7fffu + ((ua >> 16) & 1u);
    return (unsigned short)(ua >> 16);
}
static __device__ __forceinline__ unsigned bfpack(float a, float b) {
    unsigned ua = __float_as_uint(a); ua += 0x7fffu + ((ua >> 16) & 1u);
    unsigned ub = __float_as_uint(b); ub += 0x7fffu + ((ub >> 16) & 1u);
    return (ua >> 16) | (ub & 0xffff0000u);
}

// ---- K0: per-atom context flag + per-block atom count ----
__global__ __launch_bounds__(256) void k_ctx(const int* __restrict__ block_ids,
                                             const int* __restrict__ gmask,
                                             int* __restrict__ ctx,
                                             int* __restrict__ cnt) {
    int i = blockIdx.x * 256 + threadIdx.x;
    if (i < NA) {
        int b = block_ids[i];
        ctx[i] = (gmask[b] == 0) ? 1 : 0;
        atomicAdd(&cnt[b], 1);
    }
}

// ---- K1: histogram of kept edges by dst ----
__global__ __launch_bounds__(256) void k_hist(const int* __restrict__ bonds,
                                              const int* __restrict__ ctx,
                                              int* __restrict__ deg) {
    int e = blockIdx.x * 256 + threadIdx.x;
    if (e < NE) {
        int s = bonds[3 * e + 0];
        int d = bonds[3 * e + 1];
        if (ctx[s] && ctx[d]) atomicAdd(&deg[d], 1);
    }
}

// ---- K2a: dual per-chunk exclusive scan: deg->off(+totA), ctx->cpos(+totB) ----
__global__ __launch_bounds__(256) void k_scan2(const int* __restrict__ deg,
                                               const int* __restrict__ ctx,
                                               int* __restrict__ off,
                                               int* __restrict__ cpos,
                                               int* __restrict__ totA,
                                               int* __restrict__ totB) {
    __shared__ int sd[256];
    int t = threadIdx.x;
    int base = blockIdx.x * 1024 + t * 4;
    // ---- pass A: deg -> off ----
    {
        int v0 = 0, v1 = 0, v2 = 0, v3 = 0;
        if (base + 0 < NA) v0 = deg[base + 0];
        if (base + 1 < NA) v1 = deg[base + 1];
        if (base + 2 < NA) v2 = deg[base + 2];
        if (base + 3 < NA) v3 = deg[base + 3];
        int s = v0 + v1 + v2 + v3;
        sd[t] = s;
        __syncthreads();
        for (int o = 1; o < 256; o <<= 1) {
            int x = (t >= o) ? sd[t - o] : 0;
            __syncthreads();
            sd[t] += x;
            __syncthreads();
        }
        int run = sd[t] - s;
        if (t == 255) totA[blockIdx.x] = sd[255];
        if (base + 0 < NA) { off[base + 0] = run; run += v0; }
        if (base + 1 < NA) { off[base + 1] = run; run += v1; }
        if (base + 2 < NA) { off[base + 2] = run; run += v2; }
        if (base + 3 < NA) { off[base + 3] = run; }
    }
    __syncthreads();
    // ---- pass B: ctx -> cpos ----
    {
        int v0 = 0, v1 = 0, v2 = 0, v3 = 0;
        if (base + 0 < NA) v0 = ctx[base + 0];
        if (base + 1 < NA) v1 = ctx[base + 1];
        if (base + 2 < NA) v2 = ctx[base + 2];
        if (base + 3 < NA) v3 = ctx[base + 3];
        int s = v0 + v1 + v2 + v3;
        sd[t] = s;
        __syncthreads();
        for (int o = 1; o < 256; o <<= 1) {
            int x = (t >= o) ? sd[t - o] : 0;
            __syncthreads();
            sd[t] += x;
            __syncthreads();
        }
        int run = sd[t] - s;
        if (t == 255) totB[blockIdx.x] = sd[255];
        if (base + 0 < NA) { cpos[base + 0] = run; run += v0; }
        if (base + 1 < NA) { cpos[base + 1] = run; run += v1; }
        if (base + 2 < NA) { cpos[base + 2] = run; run += v2; }
        if (base + 3 < NA) { cpos[base + 3] = run; }
    }
}

// ---- K2b: scan both chunk-total arrays (single block) ----
__global__ __launch_bounds__(512) void k_scan_tot2(int* __restrict__ totA,
                                                   int* __restrict__ totB,
                                                   int* __restrict__ offNA,
                                                   int* __restrict__ nctx) {
    __shared__ int sd[512];
    int t = threadIdx.x;
    {
        int v = (t < NCHUNK) ? totA[t] : 0;
        sd[t] = v;
        __syncthreads();
        for (int o = 1; o < 512; o <<= 1) {
            int x = (t >= o) ? sd[t - o] : 0;
            __syncthreads();
            sd[t] += x;
            __syncthreads();
        }
        if (t < NCHUNK) totA[t] = sd[t] - v;
        if (t == 511) offNA[0] = sd[511];
    }
    __syncthreads();
    {
        int v = (t < NCHUNK) ? totB[t] : 0;
        sd[t] = v;
        __syncthreads();
        for (int o = 1; o < 512; o <<= 1) {
            int x = (t >= o) ? sd[t - o] : 0;
            __syncthreads();
            sd[t] += x;
            __syncthreads();
        }
        if (t < NCHUNK) totB[t] = sd[t] - v;
        if (t == 511) nctx[0] = sd[511];
    }
}

// ---- K2c: finalize edge offsets/cursors + compacted ctx-atom list ----
__global__ __launch_bounds__(256) void k_fin2(int* __restrict__ off,
                                              const int* __restrict__ totA,
                                              int* __restrict__ cur,
                                              const int* __restrict__ cpos,
                                              const int* __restrict__ totB,
                                              const int* __restrict__ ctx,
                                              int* __restrict__ catom) {
    int i = blockIdx.x * 256 + threadIdx.x;
    if (i < NA) {
        int f = off[i] + totA[i >> 10];
        off[i] = f;
        cur[i] = f;
        if (ctx[i]) catom[cpos[i] + totB[i >> 10]] = i;
    }
}

// ---- K3: scatter kept edges (combo id u16) into dst-sorted list ----
__global__ __launch_bounds__(256) void k_scatter(const int* __restrict__ bonds,
                                                 const int* __restrict__ ctx,
                                                 const int* __restrict__ A,
                                                 int* __restrict__ cur,
                                                 unsigned short* __restrict__ srt) {
    int e = blockIdx.x * 256 + threadIdx.x;
    if (e < NE) {
        int s = bonds[3 * e + 0];
        int d = bonds[3 * e + 1];
        int bt = bonds[3 * e + 2];
        if (ctx[s] && ctx[d]) {
            int p = atomicAdd(&cur[d], 1);
            srt[p] = (unsigned short)(A[s] * 5 + bt);   // < 640
        }
    }
}

// ---- Kp: precompute TAW' = (1+eps)*(atom_table@W1)+b1 ; MTW = relu(at+bt)@W1 ;
//          wt2 = bf16 col-major W2 ----
__global__ __launch_bounds__(256) void k_prep(const float* __restrict__ at,
                                              const float* __restrict__ bt,
                                              const float* __restrict__ W1,
                                              const float* __restrict__ W2,
                                              const float* __restrict__ b1,
                                              const float* __restrict__ epsp,
                                              float* __restrict__ TAW,
                                              float* __restrict__ MTW,
                                              unsigned short* __restrict__ wt2) {
    int blk = blockIdx.x;
    int tid = threadIdx.x;
    if (blk >= 384) {   // 64 blocks: W2 -> bf16 col-major [n][k]
        int id = (blk - 384) * 256 + tid;
        int n = id >> 7, k = id & 127;
        wt2[id] = bf1(W2[k * HID + n]);
        return;
    }
    __shared__ float sW1[HID * HID];
    __shared__ float sIn[2][HID];
    for (int i = tid; i < HID * HID / 4; i += 256)
        ((float4*)sW1)[i] = ((const float4*)W1)[i];
    {
        int rr = tid >> 7, k = tid & 127;
        int r = blk * 2 + rr;           // 0..767
        float v;
        if (r < 128) v = at[r * HID + k];
        else {
            int m = r - 128;
            int a = m / 5, bb = m - a * 5;
            v = fmaxf(at[a * HID + k] + bt[bb * HID + k], 0.f);
        }
        sIn[rr][k] = v;
    }
    __syncthreads();
    int rr = tid >> 7, c = tid & 127;
    int r = blk * 2 + rr;
    float acc = 0.f;
#pragma unroll 8
    for (int k = 0; k < HID; ++k)
        acc = fmaf(sIn[rr][k], sW1[k * HID + c], acc);
    if (r < 128) TAW[r * HID + c] = (1.0f + epsp[0]) * acc + b1[c];
    else         MTW[(r - 128) * HID + c] = acc;
}

// ---- K4: h1 = relu(TAW'[A] + sum MTW[cb]); segmented block-sum -> S (= out) ----
__global__ __launch_bounds__(256, 4) void k_h1(
    const int* __restrict__ A, const int* __restrict__ block_ids,
    const int* __restrict__ off, const unsigned short* __restrict__ srt,
    const int* __restrict__ catom, const int* __restrict__ nctxp,
    const float* __restrict__ TAW, const float* __restrict__ MTW,
    float* __restrict__ out)
{
    __shared__ float sH[64 * SST];
    __shared__ int sCat[64];
    __shared__ int sBid[64];

    const int nctx = nctxp[0];
    const int base = blockIdx.x * 64;
    if (base >= nctx) return;               // uniform exit
    const int tid = threadIdx.x;

    if (tid < 64) {
        int idx = base + tid;
        int g = (idx < nctx) ? catom[idx] : -1;
        sCat[tid] = g;
        sBid[tid] = (g >= 0) ? block_ids[g] : -1;
    }
    __syncthreads();

    {
        const int al = tid >> 2;            // atom-local 0..63
        const int ks = (tid & 3) * 32;      // k-segment base
        const int g = sCat[al];
        float hacc[32];
#pragma unroll
        for (int j = 0; j < 32; ++j) hacc[j] = 0.f;
        if (g >= 0) {
            const float4* tw = (const float4*)(TAW + A[g] * HID + ks);
#pragma unroll
            for (int j = 0; j < 8; ++j) {
                float4 v = tw[j];
                hacc[4 * j + 0] = v.x; hacc[4 * j + 1] = v.y;
                hacc[4 * j + 2] = v.z; hacc[4 * j + 3] = v.w;
            }
            const int e0 = off[g], e1 = off[g + 1];
            for (int e = e0; e < e1; ++e) {
                const float4* mw = (const float4*)(MTW + (int)srt[e] * HID + ks);
#pragma unroll
                for (int j = 0; j < 8; ++j) {
                    float4 v = mw[j];
                    hacc[4 * j + 0] += v.x; hacc[4 * j + 1] += v.y;
                    hacc[4 * j + 2] += v.z; hacc[4 * j + 3] += v.w;
                }
            }
        }
        float* rp = sH + al * SST + ks;
#pragma unroll
        for (int j = 0; j < 8; ++j) {
            float4 v = make_float4(fmaxf(hacc[4 * j + 0], 0.f),
                                   fmaxf(hacc[4 * j + 1], 0.f),
                                   fmaxf(hacc[4 * j + 2], 0.f),
                                   fmaxf(hacc[4 * j + 3], 0.f));
            *(float4*)(rp + 4 * j) = v;
        }
    }
    __syncthreads();

    // segmented block-sum over sorted sBid, atomics per (block,col) run
    {
        int c = tid & 127;
        int r0 = (tid >> 7) * 32;
        float run = 0.f;
        int curb = sBid[r0];
        for (int r = r0; r < r0 + 32; ++r) {
            int b = sBid[r];
            if (b != curb) {
                if (curb >= 0) atomicAdd(out + (size_t)curb * HID + c, run);
                run = 0.f;
                curb = b;
            }
            run += sH[r * SST + c];
        }
        if (curb >= 0) atomicAdd(out + (size_t)curb * HID + c, run);
    }
}

// ---- K5: out = mask ? 0 : (S@W2 + cnt*b2)/sqrt(max(cnt,1)) ; in-place on out ----
__global__ __launch_bounds__(256, 4) void k_gemm2(
    const unsigned short* __restrict__ wt2, const float* __restrict__ b2,
    const int* __restrict__ cnt, const int* __restrict__ gmask,
    float* __restrict__ out)
{
    __shared__ char lds[64 * SST * 4];      // low 16KB: bf16 S-tile; later f32 [64][SST]
    __shared__ float sCnt[64];
    __shared__ float sScale[64];
    const int base = blockIdx.x * 64;
    const int tid = threadIdx.x;

    if (tid < 64) {
        int rb = base + tid;
        float cf = 0.f, sc = 0.f;
        if (rb < NB) {
            int c = cnt[rb];
            cf = (float)c;
            sc = (gmask[rb] == 0) ? rsqrtf((float)(c < 1 ? 1 : c)) : 0.f;
        }
        sCnt[tid] = cf;
        sScale[tid] = sc;
    }

    // load S tile (rows = blocks) -> bf16 swizzled LDS
    {
        const int al = tid >> 2;
        const int ks4 = tid & 3;
        const int rb = base + al;
        float v[32];
        if (rb < NB) {
            const float4* sp = (const float4*)(out + (size_t)rb * HID + ks4 * 32);
#pragma unroll
            for (int j = 0; j < 8; ++j) {
                float4 x = sp[j];
                v[4 * j + 0] = x.x; v[4 * j + 1] = x.y;
                v[4 * j + 2] = x.z; v[4 * j + 3] = x.w;
            }
        } else {
#pragma unroll
            for (int j = 0; j < 32; ++j) v[j] = 0.f;
        }
        char* rowp = lds + al * 256;
#pragma unroll
        for (int c = 0; c < 4; ++c) {
            uint4 u;
            u.x = bfpack(v[8 * c + 0], v[8 * c + 1]);
            u.y = bfpack(v[8 * c + 2], v[8 * c + 3]);
            u.z = bfpack(v[8 * c + 4], v[8 * c + 5]);
            u.w = bfpack(v[8 * c + 6], v[8 * c + 7]);
            int chunk = (ks4 * 4 + c) ^ (al & 7);
            *(uint4*)(rowp + chunk * 16) = u;
        }
    }
    __syncthreads();

    const int w = tid >> 6;
    const int lane = tid & 63;
    const int rA = w * 16 + (lane & 15);
    const int g4 = lane >> 4;
    const int colb = lane & 15;

    f32x4 acc[8];
    {
        bf16x8 af[4];
#pragma unroll
        for (int k4 = 0; k4 < 4; ++k4) {
            int chunk = (k4 * 4 + g4) ^ (rA & 7);
            af[k4] = *(const bf16x8*)(lds + rA * 256 + chunk * 16);
        }
#pragma unroll
        for (int ct = 0; ct < 8; ++ct) {
            f32x4 a = {0.f, 0.f, 0.f, 0.f};
            const unsigned short* wp = wt2 + (ct * 16 + colb) * HID + g4 * 8;
#pragma unroll
            for (int k4 = 0; k4 < 4; ++k4) {
                bf16x8 bfr = *(const bf16x8*)(wp + k4 * 32);
                a = __builtin_amdgcn_mfma_f32_16x16x32_bf16(af[k4], bfr, a, 0, 0, 0);
            }
            acc[ct] = a;
        }
    }
    __syncthreads();   // done reading bf16 tile; reuse LDS as f32 staging

    float* sF = (float*)lds;
#pragma unroll
    for (int ct = 0; ct < 8; ++ct) {
        int col = ct * 16 + colb;
        float bv = b2[col];
#pragma unroll
        for (int r = 0; r < 4; ++r) {
            int row = w * 16 + g4 * 4 + r;
            sF[row * SST + col] = (acc[ct][r] + sCnt[row] * bv) * sScale[row];
        }
    }
    __syncthreads();

    // coalesced store back over the same rows (in-place safe: read was before)
    {
        const int al = tid >> 2;
        const int ks = (tid & 3) * 32;
        const int rb = base + al;
        if (rb < NB) {
            float4* o = (float4*)(out + (size_t)rb * HID + ks);
            const float* rp = sF + al * SST + ks;
#pragma unroll
            for (int j = 0; j < 8; ++j) o[j] = *(const float4*)(rp + 4 * j);
        }
    }
}

extern "C" void kernel_launch(void* const* d_in, const int* in_sizes, int n_in,
                              void* d_out, int out_size, void* d_ws, size_t ws_size,
                              hipStream_t stream) {
    const int* A          = (const int*)d_in[0];
    const int* bonds      = (const int*)d_in[1];
    const int* block_ids  = (const int*)d_in[2];
    const int* gmask      = (const int*)d_in[3];
    const float* atom_table = (const float*)d_in[4];
    const float* bond_table = (const float*)d_in[5];
    const float* eps      = (const float*)d_in[6];
    const float* W1       = (const float*)d_in[7];
    const float* b1       = (const float*)d_in[8];
    const float* W2       = (const float*)d_in[9];
    const float* b2       = (const float*)d_in[10];
    float* out = (float*)d_out;
    char* ws = (char*)d_ws;

    // ws layout (bytes); total ~12.83 MB
    int* deg   = (int*)(ws + 0);              // [NA]  (reused as catom after scans)
    int* cnt   = (int*)(ws + 2000000);        // [NB]  (contiguous with deg for one memset)
    int* off   = (int*)(ws + 2400000);        // [NA+1]
    int* cur   = (int*)(ws + 4400064);        // [NA]
    int* ctx   = (int*)(ws + 6400064);        // [NA]
    int* cpos  = (int*)(ws + 8400064);        // [NA]
    int* totA  = (int*)(ws + 10400064);       // [NCHUNK]
    int* totB  = (int*)(ws + 10402112);       // [NCHUNK]
    unsigned short* srt = (unsigned short*)(ws + 10404160);  // [NE]
    float* TAW = (float*)(ws + 12404160);     // [128*128]
    float* MTW = (float*)(ws + 12469696);     // [640*128]
    unsigned short* wt2 = (unsigned short*)(ws + 12797376);  // [128*128]
    int* nctx  = (int*)(ws + 12830144);       // [1]
    int* catom = deg;                         // overlay: deg dead after k_scan2

    hipMemsetAsync(deg, 0, 2400000, stream);                    // deg + cnt
    hipMemsetAsync(out, 0, (size_t)NB * HID * 4, stream);       // S accumulator

    k_ctx<<<(NA + 255) / 256, 256, 0, stream>>>(block_ids, gmask, ctx, cnt);
    k_hist<<<(NE + 255) / 256, 256, 0, stream>>>(bonds, ctx, deg);
    k_scan2<<<NCHUNK, 256, 0, stream>>>(deg, ctx, off, cpos, totA, totB);
    k_scan_tot2<<<1, 512, 0, stream>>>(totA, totB, off + NA, nctx);
    k_fin2<<<(NA + 255) / 256, 256, 0, stream>>>(off, totA, cur, cpos, totB, ctx, catom);
    k_scatter<<<(NE + 255) / 256, 256, 0, stream>>>(bonds, ctx, A, cur, srt);
    k_prep<<<448, 256, 0, stream>>>(atom_table, bond_table, W1, W2, b1, eps,
                                    TAW, MTW, wt2);
    k_h1<<<NT, 256, 0, stream>>>(A, block_ids, off, srt, catom, nctx, TAW, MTW, out);
    k_gemm2<<<NBT, 256, 0, stream>>>(wt2, b2, cnt, gmask, out);
}